// Round 2
// baseline (540.769 us; speedup 1.0000x reference)
//
#include <hip/hip_runtime.h>
#include <hip/hip_bf16.h>

typedef float  f32x4  __attribute__((ext_vector_type(4)));
typedef __bf16 bf16x8 __attribute__((ext_vector_type(8)));
typedef __bf16 bf16x4 __attribute__((ext_vector_type(4)));

__device__ __forceinline__ float silu_f(float x) {
    return x / (1.0f + __expf(-x));
}

// ---------------- LayerNorm -> bf16 ----------------
__global__ __launch_bounds__(256) void ln_kernel(const float* __restrict__ x,
                                                 const float* __restrict__ g,
                                                 const float* __restrict__ b,
                                                 __bf16* __restrict__ out) {
    int row = blockIdx.x;                     // 16384 token rows
    const float* xr = x + (long)row * 1024;
    int t = threadIdx.x;
    f32x4 v = *(const f32x4*)(xr + t * 4);
    float s  = v[0] + v[1] + v[2] + v[3];
    float ss = v[0]*v[0] + v[1]*v[1] + v[2]*v[2] + v[3]*v[3];
    #pragma unroll
    for (int off = 32; off > 0; off >>= 1) {
        s  += __shfl_down(s, off);
        ss += __shfl_down(ss, off);
    }
    __shared__ float red[8];
    int wave = t >> 6, lane = t & 63;
    if (lane == 0) { red[wave*2] = s; red[wave*2+1] = ss; }
    __syncthreads();
    float S  = red[0] + red[2] + red[4] + red[6];
    float SS = red[1] + red[3] + red[5] + red[7];
    float mean = S * (1.0f/1024.0f);
    float var  = SS * (1.0f/1024.0f) - mean*mean;
    float rstd = rsqrtf(var + 1e-5f);
    __bf16* orow = out + (long)row * 1024;
    #pragma unroll
    for (int j = 0; j < 4; j++) {
        float f = (v[j] - mean) * rstd * g[t*4+j] + b[t*4+j];
        orow[t*4+j] = (__bf16)f;
    }
}

// ---------------- T5 relative bias matrix (256x256, fp32) ----------------
__global__ __launch_bounds__(256) void relbias_kernel(const float* __restrict__ rel_emb,
                                                      float* __restrict__ bmat) {
    int idx = blockIdx.x * 256 + threadIdx.x;   // 65536
    int i = idx >> 8, j = idx & 255;
    int n = i - j;
    int ret = (n < 0) ? 16 : 0;                 // NUM_BUCKETS/2
    int an = (n < 0) ? -n : n;
    int bucket;
    if (an < 8) {
        bucket = ret + an;
    } else {
        float vl = logf((float)an * 0.125f) / 2.772588722239781f * 8.0f;
        int lv = 8 + (int)vl;
        bucket = ret + (lv < 15 ? lv : 15);
    }
    bmat[idx] = rel_emb[bucket] * 11.313708498984761f;   // * sqrt(128)
}

// ---------------- transpose (rows x cols) fp32 -> bf16 (cols x rows) ----------------
__global__ __launch_bounds__(256) void transpose_kernel(const float* __restrict__ in,
                                                        __bf16* __restrict__ out,
                                                        int rows, int cols) {
    __shared__ __bf16 tile[32][33];
    int c0 = blockIdx.x * 32, r0 = blockIdx.y * 32;
    int lx = threadIdx.x, ly = threadIdx.y;   // blockDim (32,8)
    #pragma unroll
    for (int i = 0; i < 4; i++) {
        int r = ly + i*8;
        tile[r][lx] = (__bf16)in[(long)(r0 + r) * cols + c0 + lx];
    }
    __syncthreads();
    #pragma unroll
    for (int i = 0; i < 4; i++) {
        int c = ly + i*8;
        out[(long)(c0 + c) * rows + r0 + lx] = tile[lx][c];
    }
}

// ---------------- generic MFMA GEMM: C[m][n] = sum_k A[m][k] * B[n][k] ----------------
// A: (M x K) row-major bf16, B: (N x K) row-major bf16 (i.e. B^T of math B).
// 128x128 block tile, BK=32, 4 waves (2x2), each wave 64x64 = 4x4 frags of 16x16x32.
struct GP {
    const __bf16* A;
    const __bf16* B;
    const __bf16* A2;
    const __bf16* B2;
    int lda, ldb, kSteps;
    long sAz, sBz, sCz;
    float scale;
    float* outF;
    __bf16 *o0, *o1, *o2, *o3;
    const float *c0, *c1, *c2;
    __bf16* gbuf;
};

// EPI: 0=H(silu; v stored transposed to vT, gate token-major)
//      1=QK(silu+4 heads; lkT stored transposed)
//      2=SIM(/256+bias, relu^2)
//      4=LINKV(/4096, transposed store)
//      6=FINAL(+b_o+x, fp32)
template<int EPI>
__global__ __launch_bounds__(256, 2) void gemm_kernel(GP p) {
    __shared__ __bf16 As[128*32];
    __shared__ __bf16 Bs[128*32];
    int z = blockIdx.z;
    const __bf16* A = p.A + (long)z * p.sAz + (long)blockIdx.x * 128 * p.lda;
    const __bf16* B = p.B + (long)z * p.sBz + (long)blockIdx.y * 128 * p.ldb;
    int tid = threadIdx.x;
    int wave = tid >> 6, lane = tid & 63;
    int wr = (wave >> 1) * 64, wc = (wave & 1) * 64;
    int lr = lane & 15, kg = lane >> 4;

    f32x4 acc[4][4] = {};

    int srow = tid >> 2;          // 0..63
    int scol = (tid & 3) * 8;     // 0,8,16,24
    for (int ks = 0; ks < p.kSteps; ++ks) {
        long k0 = (long)ks * 32;
        __syncthreads();
        *(f32x4*)(As + srow*32 + scol)      = *(const f32x4*)(A + (long)srow * p.lda + k0 + scol);
        *(f32x4*)(As + (srow+64)*32 + scol) = *(const f32x4*)(A + (long)(srow+64) * p.lda + k0 + scol);
        *(f32x4*)(Bs + srow*32 + scol)      = *(const f32x4*)(B + (long)srow * p.ldb + k0 + scol);
        *(f32x4*)(Bs + (srow+64)*32 + scol) = *(const f32x4*)(B + (long)(srow+64) * p.ldb + k0 + scol);
        __syncthreads();
        bf16x8 af[4], bfr[4];
        #pragma unroll
        for (int i = 0; i < 4; i++) af[i]  = *(const bf16x8*)(As + (wr + i*16 + lr)*32 + kg*8);
        #pragma unroll
        for (int i = 0; i < 4; i++) bfr[i] = *(const bf16x8*)(Bs + (wc + i*16 + lr)*32 + kg*8);
        #pragma unroll
        for (int i = 0; i < 4; i++)
            #pragma unroll
            for (int j = 0; j < 4; j++)
                acc[i][j] = __builtin_amdgcn_mfma_f32_16x16x32_bf16(af[i], bfr[j], acc[i][j], 0, 0, 0);
    }

    int bx = blockIdx.x, by = blockIdx.y;
    #pragma unroll
    for (int i = 0; i < 4; i++) {
        #pragma unroll
        for (int j = 0; j < 4; j++) {
            int row0 = bx*128 + wr + i*16 + kg*4;     // q = 0..3 rows are row0..row0+3
            int col  = by*128 + wc + j*16 + lr;
            if constexpr (EPI == 0) {
                if (col < 2048) {
                    bf16x4 vv;
                    #pragma unroll
                    for (int q = 0; q < 4; q++) vv[q] = (__bf16)silu_f(acc[i][j][q] + p.c0[col]);
                    *(bf16x4*)(p.o0 + (long)col*16384 + row0) = vv;     // vT[e][t]
                } else {
                    #pragma unroll
                    for (int q = 0; q < 4; q++)
                        p.o1[(long)(row0+q)*2048 + (col - 2048)] = (__bf16)silu_f(acc[i][j][q] + p.c0[col]);
                }
            } else if constexpr (EPI == 1) {
                float sv[4];
                #pragma unroll
                for (int q = 0; q < 4; q++) sv[q] = silu_f(acc[i][j][q] + p.c0[col]);
                #pragma unroll
                for (int q = 0; q < 4; q++) {
                    p.o0[(long)(row0+q)*128 + col] = (__bf16)(sv[q] * p.c1[      col] + p.c2[      col]);
                    p.o1[(long)(row0+q)*128 + col] = (__bf16)(sv[q] * p.c1[256 + col] + p.c2[256 + col]);
                    p.o2[(long)(row0+q)*128 + col] = (__bf16)(sv[q] * p.c1[128 + col] + p.c2[128 + col]);
                }
                bf16x4 lk;
                #pragma unroll
                for (int q = 0; q < 4; q++) lk[q] = (__bf16)(sv[q] * p.c1[384 + col] + p.c2[384 + col]);
                *(bf16x4*)(p.o3 + (long)col*16384 + row0) = lk;         // lkT[d][t]
            } else if constexpr (EPI == 2) {
                #pragma unroll
                for (int q = 0; q < 4; q++) {
                    int row = row0 + q;                                  // 0..255 within group
                    float s = acc[i][j][q] * (1.0f/256.0f) + p.c0[row*256 + col];
                    s = fmaxf(s, 0.0f);
                    p.o0[(long)z*p.sCz + (long)row*256 + col] = (__bf16)(s * s);
                }
            } else if constexpr (EPI == 4) {
                bf16x4 vv;
                #pragma unroll
                for (int q = 0; q < 4; q++) vv[q] = (__bf16)(acc[i][j][q] * p.scale);
                *(bf16x4*)(p.o0 + (long)z*p.sCz + (long)col*128 + row0) = vv;   // lkvT[e][d]
            } else if constexpr (EPI == 6) {
                #pragma unroll
                for (int q = 0; q < 4; q++) {
                    long idx = (long)(row0+q)*1024 + col;
                    p.outF[idx] = acc[i][j][q] + p.c0[col] + p.c1[idx];
                }
            }
        }
    }
}

// ---------------- fused quad_out + lin_out + gate (in-place into gate buffer) ----------------
// grid (2, 16, 64): z = group. acc = attn_g @ v_g  +  lin_q @ lin_kv; gate[idx] *= acc.
__global__ __launch_bounds__(256, 2) void quadlin_kernel(GP p) {
    __shared__ __bf16 As[128*32];
    __shared__ __bf16 Bs[128*32];
    int z = blockIdx.z;            // group 0..63
    int batch = z >> 4;
    int tid = threadIdx.x;
    int wave = tid >> 6, lane = tid & 63;
    int wr = (wave >> 1) * 64, wc = (wave & 1) * 64;
    int lr = lane & 15, kg = lane >> 4;
    int srow = tid >> 2;
    int scol = (tid & 3) * 8;

    f32x4 acc[4][4] = {};

    // pass 1: attn (256x256, row-major) @ v -> B = vT (e-major, ld 16384), K = 256 group tokens
    {
        const __bf16* A = p.A + (long)z * 65536 + (long)blockIdx.x * 128 * 256;
        const __bf16* B = p.B + (long)z * 256 + (long)blockIdx.y * 128 * 16384;
        for (int ks = 0; ks < 8; ++ks) {
            long k0 = (long)ks * 32;
            __syncthreads();
            *(f32x4*)(As + srow*32 + scol)      = *(const f32x4*)(A + (long)srow * 256 + k0 + scol);
            *(f32x4*)(As + (srow+64)*32 + scol) = *(const f32x4*)(A + (long)(srow+64) * 256 + k0 + scol);
            *(f32x4*)(Bs + srow*32 + scol)      = *(const f32x4*)(B + (long)srow * 16384 + k0 + scol);
            *(f32x4*)(Bs + (srow+64)*32 + scol) = *(const f32x4*)(B + (long)(srow+64) * 16384 + k0 + scol);
            __syncthreads();
            bf16x8 af[4], bfr[4];
            #pragma unroll
            for (int i = 0; i < 4; i++) af[i]  = *(const bf16x8*)(As + (wr + i*16 + lr)*32 + kg*8);
            #pragma unroll
            for (int i = 0; i < 4; i++) bfr[i] = *(const bf16x8*)(Bs + (wc + i*16 + lr)*32 + kg*8);
            #pragma unroll
            for (int i = 0; i < 4; i++)
                #pragma unroll
                for (int j = 0; j < 4; j++)
                    acc[i][j] = __builtin_amdgcn_mfma_f32_16x16x32_bf16(af[i], bfr[j], acc[i][j], 0, 0, 0);
        }
    }
    // pass 2: lin_q (token-major, ld 128) @ lin_kv -> B = lkvT (e-major, ld 128), K = 128
    {
        const __bf16* A = p.A2 + ((long)z * 256 + (long)blockIdx.x * 128) * 128;
        const __bf16* B = p.B2 + (long)batch * 2048 * 128 + (long)blockIdx.y * 128 * 128;
        for (int ks = 0; ks < 4; ++ks) {
            long k0 = (long)ks * 32;
            __syncthreads();
            *(f32x4*)(As + srow*32 + scol)      = *(const f32x4*)(A + (long)srow * 128 + k0 + scol);
            *(f32x4*)(As + (srow+64)*32 + scol) = *(const f32x4*)(A + (long)(srow+64) * 128 + k0 + scol);
            *(f32x4*)(Bs + srow*32 + scol)      = *(const f32x4*)(B + (long)srow * 128 + k0 + scol);
            *(f32x4*)(Bs + (srow+64)*32 + scol) = *(const f32x4*)(B + (long)(srow+64) * 128 + k0 + scol);
            __syncthreads();
            bf16x8 af[4], bfr[4];
            #pragma unroll
            for (int i = 0; i < 4; i++) af[i]  = *(const bf16x8*)(As + (wr + i*16 + lr)*32 + kg*8);
            #pragma unroll
            for (int i = 0; i < 4; i++) bfr[i] = *(const bf16x8*)(Bs + (wc + i*16 + lr)*32 + kg*8);
            #pragma unroll
            for (int i = 0; i < 4; i++)
                #pragma unroll
                for (int j = 0; j < 4; j++)
                    acc[i][j] = __builtin_amdgcn_mfma_f32_16x16x32_bf16(af[i], bfr[j], acc[i][j], 0, 0, 0);
        }
    }
    // epilogue: gate[t][e] = gate * (quad + lin)   (in place; each thread owns its element)
    #pragma unroll
    for (int i = 0; i < 4; i++) {
        #pragma unroll
        for (int j = 0; j < 4; j++) {
            int row0 = z*256 + blockIdx.x*128 + wr + i*16 + kg*4;   // global token
            int col  = blockIdx.y*128 + wc + j*16 + lr;             // e
            #pragma unroll
            for (int q = 0; q < 4; q++) {
                long idx = (long)(row0+q)*2048 + col;
                float g = (float)p.gbuf[idx];
                p.gbuf[idx] = (__bf16)(g * acc[i][j][q]);
            }
        }
    }
}

extern "C" void kernel_launch(void* const* d_in, const int* in_sizes, int n_in,
                              void* d_out, int out_size, void* d_ws, size_t ws_size,
                              hipStream_t stream) {
    const float* x       = (const float*)d_in[0];
    const float* ln_g    = (const float*)d_in[1];
    const float* ln_b    = (const float*)d_in[2];
    const float* W_h     = (const float*)d_in[3];
    const float* b_h     = (const float*)d_in[4];
    const float* W_qk    = (const float*)d_in[5];
    const float* b_qk    = (const float*)d_in[6];
    const float* os_g    = (const float*)d_in[7];
    const float* os_b    = (const float*)d_in[8];
    const float* rel_emb = (const float*)d_in[9];
    const float* W_o     = (const float*)d_in[10];
    const float* b_o     = (const float*)d_in[11];
    float* out = (float*)d_out;

    const size_t MB = 1024 * 1024;
    if (ws_size < 190 * MB) return;   // makes undersized-ws show as clean absmax fail, not a fault

    char* ws = (char*)d_ws;
    // arena layout (explicit, with lifetime-based aliasing):
    __bf16* gate = (__bf16*)(ws + 0);          // 64 MB: gate -> combined out (in place) -> GEMM<6> A
    __bf16* vT   = (__bf16*)(ws + 64*MB);      // 64 MB: v stored e-major directly by GEMM<0>
    __bf16* norm = (__bf16*)(ws + 128*MB);     // 32 MB: LN out; dead after GEMM<1>
    __bf16* attn = (__bf16*)(ws + 128*MB);     //  8 MB: aliases norm (written by GEMM<2>, after)
    __bf16* lkvT = (__bf16*)(ws + 136*MB);     //  2 MB: aliases norm tail (written by GEMM<4>)
    __bf16* qq   = (__bf16*)(ws + 160*MB);     //  4 MB
    __bf16* qk2  = (__bf16*)(ws + 164*MB);     //  4 MB
    __bf16* lq   = (__bf16*)(ws + 168*MB);     //  4 MB
    __bf16* lkT  = (__bf16*)(ws + 172*MB);     //  4 MB: lin_k^T (d-major)
    float*  bmat = (float* )(ws + 176*MB);     //  0.25 MB
    __bf16* WqkT = (__bf16*)(ws + 176*MB + 256*1024);  // 0.25 MB
    __bf16* WoT  = (__bf16*)(ws + 177*MB);     //  4 MB
    __bf16* WhT  = (__bf16*)(ws + 181*MB);     //  8 MB  -> total 189 MB

    relbias_kernel<<<256, 256, 0, stream>>>(rel_emb, bmat);
    ln_kernel<<<16384, 256, 0, stream>>>(x, ln_g, ln_b, norm);
    dim3 tb(32, 8);
    transpose_kernel<<<dim3(128, 32), tb, 0, stream>>>(W_h,  WhT,  1024, 4096);
    transpose_kernel<<<dim3(4,   32), tb, 0, stream>>>(W_qk, WqkT, 1024, 128);
    transpose_kernel<<<dim3(32,  64), tb, 0, stream>>>(W_o,  WoT,  2048, 1024);

    // hidden = silu(norm @ W_h + b_h): v -> vT (e-major), gate -> token-major
    {
        GP p{}; p.A = norm; p.B = WhT; p.lda = 1024; p.ldb = 1024; p.kSteps = 32;
        p.c0 = b_h; p.o0 = vT; p.o1 = gate;
        gemm_kernel<0><<<dim3(128, 32, 1), 256, 0, stream>>>(p);
    }
    // qk = silu(norm @ W_qk + b_qk) -> quad_q, quad_k, lin_q (token-major), lin_k^T (d-major)
    {
        GP p{}; p.A = norm; p.B = WqkT; p.lda = 1024; p.ldb = 1024; p.kSteps = 32;
        p.c0 = b_qk; p.c1 = os_g; p.c2 = os_b;
        p.o0 = qq; p.o1 = qk2; p.o2 = lq; p.o3 = lkT;
        gemm_kernel<1><<<dim3(128, 1, 1), 256, 0, stream>>>(p);
    }
    // attn = relu(qq @ qk^T / 256 + bias)^2   per group (z = 64)
    {
        GP p{}; p.A = qq; p.B = qk2; p.lda = 128; p.ldb = 128; p.kSteps = 4;
        p.sAz = 256*128; p.sBz = 256*128; p.sCz = 256*256;
        p.c0 = bmat; p.o0 = attn;
        gemm_kernel<2><<<dim3(2, 2, 64), 256, 0, stream>>>(p);
    }
    // lin_kv^T[e][d] = (sum_t lin_k[t][d] v[t][e]) / 4096   per batch (z = 4)
    {
        GP p{}; p.A = lkT; p.B = vT; p.lda = 16384; p.ldb = 16384; p.kSteps = 128;
        p.sAz = 4096; p.sBz = 4096; p.sCz = 2048*128; p.scale = 1.0f/4096.0f;
        p.o0 = lkvT;
        gemm_kernel<4><<<dim3(1, 16, 4), 256, 0, stream>>>(p);
    }
    // gate <- gate * (attn @ v + lin_q @ lin_kv)   (fused, in place)
    {
        GP p{}; p.A = attn; p.B = vT; p.A2 = lq; p.B2 = lkvT; p.gbuf = gate;
        quadlin_kernel<<<dim3(2, 16, 64), 256, 0, stream>>>(p);
    }
    // final = combined @ W_o + b_o + x
    {
        GP p{}; p.A = gate; p.B = WoT; p.lda = 2048; p.ldb = 2048; p.kSteps = 64;
        p.c0 = b_o; p.c1 = x; p.outF = out;
        gemm_kernel<6><<<dim3(128, 8, 1), 256, 0, stream>>>(p);
    }
}

// Round 3
// 518.222 us; speedup vs baseline: 1.0435x; 1.0435x over previous
//
#include <hip/hip_runtime.h>
#include <hip/hip_bf16.h>

typedef float  f32x4  __attribute__((ext_vector_type(4)));
typedef __bf16 bf16x8 __attribute__((ext_vector_type(8)));
typedef __bf16 bf16x4 __attribute__((ext_vector_type(4)));

__device__ __forceinline__ float silu_f(float x) {
    return x / (1.0f + __expf(-x));
}

// async global->LDS, 16B per lane; LDS dest = wave-uniform base + lane*16B
__device__ __forceinline__ void gload16(const __bf16* g, __bf16* l) {
    __builtin_amdgcn_global_load_lds((const __attribute__((address_space(1))) void*)g,
                                     (__attribute__((address_space(3))) void*)l, 16, 0, 0);
}

// ---------------- LayerNorm -> bf16 ----------------
__global__ __launch_bounds__(256) void ln_kernel(const float* __restrict__ x,
                                                 const float* __restrict__ g,
                                                 const float* __restrict__ b,
                                                 __bf16* __restrict__ out) {
    int row = blockIdx.x;                     // 16384 token rows
    const float* xr = x + (long)row * 1024;
    int t = threadIdx.x;
    f32x4 v = *(const f32x4*)(xr + t * 4);
    float s  = v[0] + v[1] + v[2] + v[3];
    float ss = v[0]*v[0] + v[1]*v[1] + v[2]*v[2] + v[3]*v[3];
    #pragma unroll
    for (int off = 32; off > 0; off >>= 1) {
        s  += __shfl_down(s, off);
        ss += __shfl_down(ss, off);
    }
    __shared__ float red[8];
    int wave = t >> 6, lane = t & 63;
    if (lane == 0) { red[wave*2] = s; red[wave*2+1] = ss; }
    __syncthreads();
    float S  = red[0] + red[2] + red[4] + red[6];
    float SS = red[1] + red[3] + red[5] + red[7];
    float mean = S * (1.0f/1024.0f);
    float var  = SS * (1.0f/1024.0f) - mean*mean;
    float rstd = rsqrtf(var + 1e-5f);
    __bf16* orow = out + (long)row * 1024;
    #pragma unroll
    for (int j = 0; j < 4; j++) {
        float f = (v[j] - mean) * rstd * g[t*4+j] + b[t*4+j];
        orow[t*4+j] = (__bf16)f;
    }
}

// ---------------- T5 relative bias matrix (256x256, fp32) ----------------
__global__ __launch_bounds__(256) void relbias_kernel(const float* __restrict__ rel_emb,
                                                      float* __restrict__ bmat) {
    int idx = blockIdx.x * 256 + threadIdx.x;   // 65536
    int i = idx >> 8, j = idx & 255;
    int n = i - j;
    int ret = (n < 0) ? 16 : 0;                 // NUM_BUCKETS/2
    int an = (n < 0) ? -n : n;
    int bucket;
    if (an < 8) {
        bucket = ret + an;
    } else {
        float vl = logf((float)an * 0.125f) / 2.772588722239781f * 8.0f;
        int lv = 8 + (int)vl;
        bucket = ret + (lv < 15 ? lv : 15);
    }
    bmat[idx] = rel_emb[bucket] * 11.313708498984761f;   // * sqrt(128)
}

// ---------------- transpose (rows x cols) fp32 -> bf16 (cols x rows) ----------------
__global__ __launch_bounds__(256) void transpose_kernel(const float* __restrict__ in,
                                                        __bf16* __restrict__ out,
                                                        int rows, int cols) {
    __shared__ __bf16 tile[32][33];
    int c0 = blockIdx.x * 32, r0 = blockIdx.y * 32;
    int lx = threadIdx.x, ly = threadIdx.y;   // blockDim (32,8)
    #pragma unroll
    for (int i = 0; i < 4; i++) {
        int r = ly + i*8;
        tile[r][lx] = (__bf16)in[(long)(r0 + r) * cols + c0 + lx];
    }
    __syncthreads();
    #pragma unroll
    for (int i = 0; i < 4; i++) {
        int c = ly + i*8;
        out[(long)(c0 + c) * rows + r0 + lx] = tile[lx][c];
    }
}

// ---------------- generic MFMA GEMM: C[m][n] = sum_k A[m][k] * B[n][k] ----------------
// A: (M x K) row-major bf16, B: (N x K) row-major bf16 (i.e. B^T of math B).
// 128x128 block tile, BK=32, 4 waves (2x2), each wave 64x64 = 4x4 frags of 16x16x32.
// Staging: global_load_lds width-16; wave w owns rows [32w,32w+32) of both tiles.
struct GP {
    const __bf16* A;
    const __bf16* B;
    const __bf16* A2;
    const __bf16* B2;
    int lda, ldb, kSteps;
    long sAz, sBz, sCz;
    float scale;
    float* outF;
    __bf16 *o0, *o1, *o2, *o3;
    const float *c0, *c1, *c2;
    __bf16* gbuf;
};

// EPI: 0=H(silu; v stored transposed to vT, gate token-major)
//      1=QK(silu+4 heads; lkT stored transposed)
//      2=SIM(/256+bias, relu^2)
//      4=LINKV(/4096, transposed store)
//      6=FINAL(+b_o+x, fp32)
template<int EPI>
__global__ __launch_bounds__(256, 2) void gemm_kernel(GP p) {
    __shared__ __bf16 As[128*32];
    __shared__ __bf16 Bs[128*32];
    int z = blockIdx.z;
    const __bf16* A = p.A + (long)z * p.sAz + (long)blockIdx.x * 128 * p.lda;
    const __bf16* B = p.B + (long)z * p.sBz + (long)blockIdx.y * 128 * p.ldb;
    int tid = threadIdx.x;
    int wave = tid >> 6, lane = tid & 63;
    int wr = (wave >> 1) * 64, wc = (wave & 1) * 64;
    int lr = lane & 15, kg = lane >> 4;

    f32x4 acc[4][4] = {};

    // staging addresses: lane l covers row (32*wave + l/4 [+16]), col 8*(l&3)
    int lsub = lane >> 2;
    int scol = (lane & 3) * 8;
    const __bf16* Ag = A + scol + (long)(wave*32 + lsub) * p.lda;
    const __bf16* Bg = B + scol + (long)(wave*32 + lsub) * p.ldb;
    long a16 = (long)16 * p.lda, b16 = (long)16 * p.ldb;
    __bf16* AsW = As + wave * 32 * 32;
    __bf16* BsW = Bs + wave * 32 * 32;

    for (int ks = 0; ks < p.kSteps; ++ks) {
        long k0 = (long)ks * 32;
        __syncthreads();
        gload16(Ag + k0,       AsW);
        gload16(Ag + k0 + a16, AsW + 16*32);
        gload16(Bg + k0,       BsW);
        gload16(Bg + k0 + b16, BsW + 16*32);
        __syncthreads();
        bf16x8 af[4], bfr[4];
        #pragma unroll
        for (int i = 0; i < 4; i++) af[i]  = *(const bf16x8*)(As + (wr + i*16 + lr)*32 + kg*8);
        #pragma unroll
        for (int i = 0; i < 4; i++) bfr[i] = *(const bf16x8*)(Bs + (wc + i*16 + lr)*32 + kg*8);
        #pragma unroll
        for (int i = 0; i < 4; i++)
            #pragma unroll
            for (int j = 0; j < 4; j++)
                acc[i][j] = __builtin_amdgcn_mfma_f32_16x16x32_bf16(af[i], bfr[j], acc[i][j], 0, 0, 0);
    }

    int bx = blockIdx.x, by = blockIdx.y;
    #pragma unroll
    for (int i = 0; i < 4; i++) {
        #pragma unroll
        for (int j = 0; j < 4; j++) {
            int row0 = bx*128 + wr + i*16 + kg*4;     // q = 0..3 rows are row0..row0+3
            int col  = by*128 + wc + j*16 + lr;
            if constexpr (EPI == 0) {
                if (col < 2048) {
                    bf16x4 vv;
                    #pragma unroll
                    for (int q = 0; q < 4; q++) vv[q] = (__bf16)silu_f(acc[i][j][q] + p.c0[col]);
                    *(bf16x4*)(p.o0 + (long)col*16384 + row0) = vv;     // vT[e][t]
                } else {
                    #pragma unroll
                    for (int q = 0; q < 4; q++)
                        p.o1[(long)(row0+q)*2048 + (col - 2048)] = (__bf16)silu_f(acc[i][j][q] + p.c0[col]);
                }
            } else if constexpr (EPI == 1) {
                float sv[4];
                #pragma unroll
                for (int q = 0; q < 4; q++) sv[q] = silu_f(acc[i][j][q] + p.c0[col]);
                #pragma unroll
                for (int q = 0; q < 4; q++) {
                    p.o0[(long)(row0+q)*128 + col] = (__bf16)(sv[q] * p.c1[      col] + p.c2[      col]);
                    p.o1[(long)(row0+q)*128 + col] = (__bf16)(sv[q] * p.c1[256 + col] + p.c2[256 + col]);
                    p.o2[(long)(row0+q)*128 + col] = (__bf16)(sv[q] * p.c1[128 + col] + p.c2[128 + col]);
                }
                bf16x4 lk;
                #pragma unroll
                for (int q = 0; q < 4; q++) lk[q] = (__bf16)(sv[q] * p.c1[384 + col] + p.c2[384 + col]);
                *(bf16x4*)(p.o3 + (long)col*16384 + row0) = lk;         // lkT[d][t]
            } else if constexpr (EPI == 2) {
                #pragma unroll
                for (int q = 0; q < 4; q++) {
                    int row = row0 + q;                                  // 0..255 within group
                    float s = acc[i][j][q] * (1.0f/256.0f) + p.c0[row*256 + col];
                    s = fmaxf(s, 0.0f);
                    p.o0[(long)z*p.sCz + (long)row*256 + col] = (__bf16)(s * s);
                }
            } else if constexpr (EPI == 4) {
                bf16x4 vv;
                #pragma unroll
                for (int q = 0; q < 4; q++) vv[q] = (__bf16)(acc[i][j][q] * p.scale);
                *(bf16x4*)(p.o0 + (long)z*p.sCz + (long)col*128 + row0) = vv;   // lkvT[e][d]
            } else if constexpr (EPI == 6) {
                #pragma unroll
                for (int q = 0; q < 4; q++) {
                    long idx = (long)(row0+q)*1024 + col;
                    p.outF[idx] = acc[i][j][q] + p.c0[col] + p.c1[idx];
                }
            }
        }
    }
}

// ---------------- fused quad_out + lin_out + gate (in-place into gate buffer) ----------------
// grid (2, 16, 64): z = group. acc = attn_g @ v_g  +  lin_q @ lin_kv; gate[idx] *= acc.
__global__ __launch_bounds__(256, 2) void quadlin_kernel(GP p) {
    __shared__ __bf16 As[128*32];
    __shared__ __bf16 Bs[128*32];
    int z = blockIdx.z;            // group 0..63
    int batch = z >> 4;
    int tid = threadIdx.x;
    int wave = tid >> 6, lane = tid & 63;
    int wr = (wave >> 1) * 64, wc = (wave & 1) * 64;
    int lr = lane & 15, kg = lane >> 4;
    int lsub = lane >> 2;
    int scol = (lane & 3) * 8;
    __bf16* AsW = As + wave * 32 * 32;
    __bf16* BsW = Bs + wave * 32 * 32;

    f32x4 acc[4][4] = {};

    // pass 1: attn (256x256, row-major) @ v -> B = vT (e-major, ld 16384), K = 256 group tokens
    {
        const __bf16* Ag = p.A + (long)z * 65536 + (long)blockIdx.x * 128 * 256
                         + scol + (long)(wave*32 + lsub) * 256;
        const __bf16* Bg = p.B + (long)z * 256 + (long)blockIdx.y * 128 * 16384
                         + scol + (long)(wave*32 + lsub) * 16384;
        for (int ks = 0; ks < 8; ++ks) {
            long k0 = (long)ks * 32;
            __syncthreads();
            gload16(Ag + k0,            AsW);
            gload16(Ag + k0 + 16*256,   AsW + 16*32);
            gload16(Bg + k0,            BsW);
            gload16(Bg + k0 + 16L*16384, BsW + 16*32);
            __syncthreads();
            bf16x8 af[4], bfr[4];
            #pragma unroll
            for (int i = 0; i < 4; i++) af[i]  = *(const bf16x8*)(As + (wr + i*16 + lr)*32 + kg*8);
            #pragma unroll
            for (int i = 0; i < 4; i++) bfr[i] = *(const bf16x8*)(Bs + (wc + i*16 + lr)*32 + kg*8);
            #pragma unroll
            for (int i = 0; i < 4; i++)
                #pragma unroll
                for (int j = 0; j < 4; j++)
                    acc[i][j] = __builtin_amdgcn_mfma_f32_16x16x32_bf16(af[i], bfr[j], acc[i][j], 0, 0, 0);
        }
    }
    // pass 2: lin_q (token-major, ld 128) @ lin_kv -> B = lkvT (e-major, ld 128), K = 128
    {
        const __bf16* Ag = p.A2 + ((long)z * 256 + (long)blockIdx.x * 128) * 128
                         + scol + (long)(wave*32 + lsub) * 128;
        const __bf16* Bg = p.B2 + (long)batch * 2048 * 128 + (long)blockIdx.y * 128 * 128
                         + scol + (long)(wave*32 + lsub) * 128;
        for (int ks = 0; ks < 4; ++ks) {
            long k0 = (long)ks * 32;
            __syncthreads();
            gload16(Ag + k0,           AsW);
            gload16(Ag + k0 + 16*128,  AsW + 16*32);
            gload16(Bg + k0,           BsW);
            gload16(Bg + k0 + 16*128,  BsW + 16*32);
            __syncthreads();
            bf16x8 af[4], bfr[4];
            #pragma unroll
            for (int i = 0; i < 4; i++) af[i]  = *(const bf16x8*)(As + (wr + i*16 + lr)*32 + kg*8);
            #pragma unroll
            for (int i = 0; i < 4; i++) bfr[i] = *(const bf16x8*)(Bs + (wc + i*16 + lr)*32 + kg*8);
            #pragma unroll
            for (int i = 0; i < 4; i++)
                #pragma unroll
                for (int j = 0; j < 4; j++)
                    acc[i][j] = __builtin_amdgcn_mfma_f32_16x16x32_bf16(af[i], bfr[j], acc[i][j], 0, 0, 0);
        }
    }
    // epilogue: gate[t][e] = gate * (quad + lin)   (in place; each thread owns its element)
    #pragma unroll
    for (int i = 0; i < 4; i++) {
        #pragma unroll
        for (int j = 0; j < 4; j++) {
            int row0 = z*256 + blockIdx.x*128 + wr + i*16 + kg*4;   // global token
            int col  = blockIdx.y*128 + wc + j*16 + lr;             // e
            #pragma unroll
            for (int q = 0; q < 4; q++) {
                long idx = (long)(row0+q)*2048 + col;
                float g = (float)p.gbuf[idx];
                p.gbuf[idx] = (__bf16)(g * acc[i][j][q]);
            }
        }
    }
}

extern "C" void kernel_launch(void* const* d_in, const int* in_sizes, int n_in,
                              void* d_out, int out_size, void* d_ws, size_t ws_size,
                              hipStream_t stream) {
    const float* x       = (const float*)d_in[0];
    const float* ln_g    = (const float*)d_in[1];
    const float* ln_b    = (const float*)d_in[2];
    const float* W_h     = (const float*)d_in[3];
    const float* b_h     = (const float*)d_in[4];
    const float* W_qk    = (const float*)d_in[5];
    const float* b_qk    = (const float*)d_in[6];
    const float* os_g    = (const float*)d_in[7];
    const float* os_b    = (const float*)d_in[8];
    const float* rel_emb = (const float*)d_in[9];
    const float* W_o     = (const float*)d_in[10];
    const float* b_o     = (const float*)d_in[11];
    float* out = (float*)d_out;

    const size_t MB = 1024 * 1024;
    if (ws_size < 190 * MB) return;   // undersized-ws shows as clean absmax fail, not a fault

    char* ws = (char*)d_ws;
    // arena layout (explicit, with lifetime-based aliasing):
    __bf16* gate = (__bf16*)(ws + 0);          // 64 MB: gate -> combined out (in place) -> GEMM<6> A
    __bf16* vT   = (__bf16*)(ws + 64*MB);      // 64 MB: v stored e-major directly by GEMM<0>
    __bf16* norm = (__bf16*)(ws + 128*MB);     // 32 MB: LN out; dead after GEMM<1>
    __bf16* attn = (__bf16*)(ws + 128*MB);     //  8 MB: aliases norm (written by GEMM<2>, after)
    __bf16* lkvT = (__bf16*)(ws + 136*MB);     //  2 MB: aliases norm tail (written by GEMM<4>)
    __bf16* qq   = (__bf16*)(ws + 160*MB);     //  4 MB
    __bf16* qk2  = (__bf16*)(ws + 164*MB);     //  4 MB
    __bf16* lq   = (__bf16*)(ws + 168*MB);     //  4 MB
    __bf16* lkT  = (__bf16*)(ws + 172*MB);     //  4 MB: lin_k^T (d-major)
    float*  bmat = (float* )(ws + 176*MB);     //  0.25 MB
    __bf16* WqkT = (__bf16*)(ws + 176*MB + 256*1024);  // 0.25 MB
    __bf16* WoT  = (__bf16*)(ws + 177*MB);     //  4 MB
    __bf16* WhT  = (__bf16*)(ws + 181*MB);     //  8 MB  -> total 189 MB

    relbias_kernel<<<256, 256, 0, stream>>>(rel_emb, bmat);
    ln_kernel<<<16384, 256, 0, stream>>>(x, ln_g, ln_b, norm);
    dim3 tb(32, 8);
    transpose_kernel<<<dim3(128, 32), tb, 0, stream>>>(W_h,  WhT,  1024, 4096);
    transpose_kernel<<<dim3(4,   32), tb, 0, stream>>>(W_qk, WqkT, 1024, 128);
    transpose_kernel<<<dim3(32,  64), tb, 0, stream>>>(W_o,  WoT,  2048, 1024);

    // hidden = silu(norm @ W_h + b_h): v -> vT (e-major), gate -> token-major
    {
        GP p{}; p.A = norm; p.B = WhT; p.lda = 1024; p.ldb = 1024; p.kSteps = 32;
        p.c0 = b_h; p.o0 = vT; p.o1 = gate;
        gemm_kernel<0><<<dim3(128, 32, 1), 256, 0, stream>>>(p);
    }
    // qk = silu(norm @ W_qk + b_qk) -> quad_q, quad_k, lin_q (token-major), lin_k^T (d-major)
    {
        GP p{}; p.A = norm; p.B = WqkT; p.lda = 1024; p.ldb = 1024; p.kSteps = 32;
        p.c0 = b_qk; p.c1 = os_g; p.c2 = os_b;
        p.o0 = qq; p.o1 = qk2; p.o2 = lq; p.o3 = lkT;
        gemm_kernel<1><<<dim3(128, 1, 1), 256, 0, stream>>>(p);
    }
    // attn = relu(qq @ qk^T / 256 + bias)^2   per group (z = 64)
    {
        GP p{}; p.A = qq; p.B = qk2; p.lda = 128; p.ldb = 128; p.kSteps = 4;
        p.sAz = 256*128; p.sBz = 256*128; p.sCz = 256*256;
        p.c0 = bmat; p.o0 = attn;
        gemm_kernel<2><<<dim3(2, 2, 64), 256, 0, stream>>>(p);
    }
    // lin_kv^T[e][d] = (sum_t lin_k[t][d] v[t][e]) / 4096   per batch (z = 4)
    {
        GP p{}; p.A = lkT; p.B = vT; p.lda = 16384; p.ldb = 16384; p.kSteps = 128;
        p.sAz = 4096; p.sBz = 4096; p.sCz = 2048*128; p.scale = 1.0f/4096.0f;
        p.o0 = lkvT;
        gemm_kernel<4><<<dim3(1, 16, 4), 256, 0, stream>>>(p);
    }
    // gate <- gate * (attn @ v + lin_q @ lin_kv)   (fused, in place)
    {
        GP p{}; p.A = attn; p.B = vT; p.A2 = lq; p.B2 = lkvT; p.gbuf = gate;
        quadlin_kernel<<<dim3(2, 16, 64), 256, 0, stream>>>(p);
    }
    // final = combined @ W_o + b_o + x
    {
        GP p{}; p.A = gate; p.B = WoT; p.lda = 2048; p.ldb = 2048; p.kSteps = 64;
        p.c0 = b_o; p.c1 = x; p.outF = out;
        gemm_kernel<6><<<dim3(128, 8, 1), 256, 0, stream>>>(p);
    }
}